// Round 1
// baseline (308.601 us; speedup 1.0000x reference)
//
#include <hip/hip_runtime.h>

// ---------------------------------------------------------------------------
// Problem: TextureAnalysisModule
//  x: (16,3,1024,1024) f32 -> patch scores (1024) -> top9/bot9 -> recon 96x96
//  -> bilinear resize 224x224 (jax half-pixel) -> depthwise 3x3 SRM conv
//  out: (2,16,3,224,224) f32
// ---------------------------------------------------------------------------

#define NSLICE 48          // B*C = 16*3
#define IMG    1048576     // 1024*1024

// K1: one block per patch position (1024 blocks, 256 threads).
// Per (b,c) slice: stage 32x32 tile in LDS, accumulate |dx|,dx^2,|dy|,dy^2 in
// doubles (ordering of near-tied scores demands better-than-f32 accumulation).
__global__ __launch_bounds__(256) void k_score(const float* __restrict__ x,
                                               double* __restrict__ scores) {
  const int p  = blockIdx.x;
  const int ph = p >> 5, pw = p & 31;
  __shared__ float tile[32][33];
  __shared__ double wsum[4][4];
  const int t   = threadIdx.x;
  const int row = t >> 3;
  const int c4  = (t & 7) << 2;

  double s1x = 0.0, s2x = 0.0, s1y = 0.0, s2y = 0.0;

  const float* pr = x + (size_t)ph * (32 * 1024) + (size_t)pw * 32
                      + (size_t)row * 1024 + c4;
  float4 v = *(const float4*)pr;

  for (int s = 0; s < NSLICE; ++s) {
    tile[row][c4]     = v.x;
    tile[row][c4 + 1] = v.y;
    tile[row][c4 + 2] = v.z;
    tile[row][c4 + 3] = v.w;
    __syncthreads();

    float4 vn = v;
    if (s + 1 < NSLICE) vn = *(const float4*)(pr + (size_t)(s + 1) * IMG);

    // dx diffs at columns c4..c4+3 (col 31 has none)
    float d0 = fabsf(v.y - v.x);
    float d1 = fabsf(v.z - v.y);
    float d2 = fabsf(v.w - v.z);
    s1x += d0; s2x += (double)d0 * d0;
    s1x += d1; s2x += (double)d1 * d1;
    s1x += d2; s2x += (double)d2 * d2;
    if (c4 < 28) {
      float r4 = tile[row][c4 + 4];
      float d3 = fabsf(r4 - v.w);
      s1x += d3; s2x += (double)d3 * d3;
    }
    // dy diffs between row and row+1
    if (row < 31) {
      float b0 = tile[row + 1][c4];
      float b1 = tile[row + 1][c4 + 1];
      float b2 = tile[row + 1][c4 + 2];
      float b3 = tile[row + 1][c4 + 3];
      float e0 = fabsf(b0 - v.x);
      float e1 = fabsf(b1 - v.y);
      float e2 = fabsf(b2 - v.z);
      float e3 = fabsf(b3 - v.w);
      s1y += e0; s2y += (double)e0 * e0;
      s1y += e1; s2y += (double)e1 * e1;
      s1y += e2; s2y += (double)e2 * e2;
      s1y += e3; s2y += (double)e3 * e3;
    }
    __syncthreads();
    v = vn;
  }

  // wave reduce (64 lanes) then cross-wave via LDS
#pragma unroll
  for (int off = 32; off > 0; off >>= 1) {
    s1x += __shfl_down(s1x, off);
    s2x += __shfl_down(s2x, off);
    s1y += __shfl_down(s1y, off);
    s2y += __shfl_down(s2y, off);
  }
  const int wave = t >> 6, lane = t & 63;
  if (lane == 0) {
    wsum[0][wave] = s1x; wsum[1][wave] = s2x;
    wsum[2][wave] = s1y; wsum[3][wave] = s2y;
  }
  __syncthreads();
  if (t == 0) {
    double S1x = wsum[0][0] + wsum[0][1] + wsum[0][2] + wsum[0][3];
    double S2x = wsum[1][0] + wsum[1][1] + wsum[1][2] + wsum[1][3];
    double S1y = wsum[2][0] + wsum[2][1] + wsum[2][2] + wsum[2][3];
    double S2y = wsum[3][0] + wsum[3][1] + wsum[3][2] + wsum[3][3];
    const double N = 47616.0;  // 16*3*32*31
    double mx = S1x / N, my = S1y / N;
    double vx = (S2x - S1x * S1x / N) / (N - 1.0);
    double vy = (S2y - S1y * S1y / N) / (N - 1.0);
    scores[p] = 0.25 * (mx + my) * (vx + vy);
  }
}

// K2: stable rank-by-counting over 1024 scores; scatter the 18 selected
// patch indices. sel[0..8] = rich (ranks 1015..1023 asc), sel[9..17] = poor.
__global__ void k_select(const double* __restrict__ scores,
                         int* __restrict__ sel) {
  __shared__ double s[1024];
  const int t = threadIdx.x;
  s[t] = scores[t];
  __syncthreads();
  const double mine = s[t];
  int rank = 0;
  for (int j = 0; j < 1024; ++j) {
    double vj = s[j];
    rank += (vj < mine) || (vj == mine && j < t);
  }
  if (rank < 9)          sel[9 + rank]    = t;   // poor, ascending
  else if (rank >= 1015) sel[rank - 1015] = t;   // rich, ascending
}

// K3: one block per (set,b,c) image. Gather 9 patches -> LDS recon[96][97],
// then fused {bilinear 96->224 (half-pixel, clamp edge) + 3x3 SRM conv}.
__global__ __launch_bounds__(256) void k_output(const float* __restrict__ x,
                                                const int* __restrict__ sel,
                                                float* __restrict__ out) {
  const int blk = blockIdx.x;      // 0..95 ; = set*48 + (b*3+c)
  const int set = blk / 48;
  const int bc  = blk % 48;
  __shared__ float R[96][97];
  __shared__ int   i0t[224];
  __shared__ float frt[224];
  __shared__ int   selm[9];
  const int t = threadIdx.x;

  if (t < 9) selm[t] = sel[set * 9 + t];
  if (t < 224) {
    // src coord = (t+0.5)*96/224 - 0.5 = (3t-2)/7 exactly
    int num = 3 * t - 2;
    int i0, fr7;
    if (num < 0) { i0 = 0; fr7 = 0; }
    else {
      i0 = num / 7; fr7 = num - i0 * 7;
      if (i0 >= 95) { i0 = 95; fr7 = 0; }
    }
    i0t[t] = i0;
    frt[t] = (float)fr7 * (1.0f / 7.0f);
  }
  __syncthreads();

  const float* src = x + (size_t)bc * IMG;
  for (int idx = t; idx < 96 * 96; idx += 256) {
    int y  = idx / 96, xx = idx - y * 96;
    int gr = y >> 5, i = y & 31;
    int gc = xx >> 5, j = xx & 31;
    int pidx = selm[gr * 3 + gc];
    R[y][xx] = src[(size_t)((pidx >> 5) * 32 + i) * 1024 + (pidx & 31) * 32 + j];
  }
  __syncthreads();

  const float F[3][3] = {{-1.f, 3.f, -1.f}, {3.f, -8.f, 3.f}, {-1.f, 3.f, -1.f}};
  float* o = out + (size_t)blk * (224 * 224);

  for (int idx = t; idx < 224 * 224; idx += 256) {
    int y  = idx / 224;
    int xx = idx - y * 224;
    float acc = 0.f;
#pragma unroll
    for (int dy = 0; dy < 3; ++dy) {
      int Y = y + dy - 1;
      if ((unsigned)Y >= 224u) continue;     // zero padding
      int   iy0 = i0t[Y];
      int   iy1 = min(iy0 + 1, 95);
      float fy  = frt[Y];
#pragma unroll
      for (int dx = 0; dx < 3; ++dx) {
        int X = xx + dx - 1;
        if ((unsigned)X >= 224u) continue;   // zero padding
        int   ix0 = i0t[X];
        int   ix1 = min(ix0 + 1, 95);
        float fx  = frt[X];
        float v00 = R[iy0][ix0], v01 = R[iy0][ix1];
        float v10 = R[iy1][ix0], v11 = R[iy1][ix1];
        float top = v00 + fx * (v01 - v00);
        float bot = v10 + fx * (v11 - v10);
        float val = top + fy * (bot - top);
        acc += F[dy][dx] * val;
      }
    }
    o[idx] = acc;
  }
}

extern "C" void kernel_launch(void* const* d_in, const int* in_sizes, int n_in,
                              void* d_out, int out_size, void* d_ws, size_t ws_size,
                              hipStream_t stream) {
  const float* x = (const float*)d_in[0];
  float* out = (float*)d_out;

  double* scores = (double*)d_ws;                       // 1024 * 8 B
  int*    sel    = (int*)((char*)d_ws + 8192);          // 18 * 4 B

  k_score <<<1024, 256, 0, stream>>>(x, scores);
  k_select<<<1, 1024, 0, stream>>>(scores, sel);
  k_output<<<96, 256, 0, stream>>>(x, sel, out);
}

// Round 2
// 112.634 us; speedup vs baseline: 2.7398x; 2.7398x over previous
//
#include <hip/hip_runtime.h>

// ---------------------------------------------------------------------------
// TextureAnalysisModule: x (16,3,1024,1024) f32
//  -> per-patch gradient scores (1024)  [k_score: contiguous strips + f64 atomics]
//  -> stable top-9 / bottom-9           [k_select: rank-by-counting]
//  -> 96x96 recon -> bilinear 224 (half-pixel) -> 3x3 SRM conv
//     [k_output: 8-row output strips, 2688 blocks]
//  out: (2,16,3,224,224) f32
// ---------------------------------------------------------------------------

#define NSLICE 48          // B*C
#define IMG    1048576     // 1024*1024
#define TILE   8           // output rows per k_output block

// K1: one block per (patch-row, slice). Reads a contiguous 32x1024 strip.
// Thread t owns columns 4t..4t+3 every row; dx neighbor via shfl (lane t%8==7
// sits on a patch boundary -> no cross-wave case); dy via previous-row regs.
// Doubles for accumulation: near-tied scores demand high-precision sums.
__global__ __launch_bounds__(256) void k_score(const float* __restrict__ x,
                                               double* __restrict__ accum) {
  const int ph = blockIdx.x;   // patch row 0..31
  const int s  = blockIdx.y;   // slice 0..47
  const int t  = threadIdx.x;
  const float* base = x + (size_t)s * IMG + (size_t)ph * 32768 + 4 * t;

  double s1x = 0.0, s2x = 0.0, s1y = 0.0, s2y = 0.0;
  const bool has_d3 = (t & 7) != 7;   // col 4t+3 not a patch boundary
  float4 prev = make_float4(0.f, 0.f, 0.f, 0.f);

  for (int r = 0; r < 32; ++r) {
    float4 v = *(const float4*)(base + (size_t)r * 1024);
    float nx = __shfl_down(v.x, 1);          // lane t+1's first element
    float d0 = fabsf(v.y - v.x);
    float d1 = fabsf(v.z - v.y);
    float d2 = fabsf(v.w - v.z);
    s1x += d0; s2x += (double)d0 * d0;
    s1x += d1; s2x += (double)d1 * d1;
    s1x += d2; s2x += (double)d2 * d2;
    if (has_d3) {
      float d3 = fabsf(nx - v.w);
      s1x += d3; s2x += (double)d3 * d3;
    }
    if (r > 0) {
      float e0 = fabsf(v.x - prev.x);
      float e1 = fabsf(v.y - prev.y);
      float e2 = fabsf(v.z - prev.z);
      float e3 = fabsf(v.w - prev.w);
      s1y += e0; s2y += (double)e0 * e0;
      s1y += e1; s2y += (double)e1 * e1;
      s1y += e2; s2y += (double)e2 * e2;
      s1y += e3; s2y += (double)e3 * e3;
    }
    prev = v;
  }

  // reduce within each 8-lane group (one patch per group)
#pragma unroll
  for (int off = 4; off > 0; off >>= 1) {
    s1x += __shfl_down(s1x, off, 8);
    s2x += __shfl_down(s2x, off, 8);
    s1y += __shfl_down(s1y, off, 8);
    s2y += __shfl_down(s2y, off, 8);
  }
  if ((t & 7) == 0) {
    const int p = ph * 32 + (t >> 3);
    double* a = accum + 4 * p;
    atomicAdd(a + 0, s1x);
    atomicAdd(a + 1, s2x);
    atomicAdd(a + 2, s1y);
    atomicAdd(a + 3, s2y);
  }
}

// K2: finalize scores + stable rank-by-counting; scatter 18 selected indices.
// sel[0..8] = rich (ranks 1015..1023 asc), sel[9..17] = poor (ranks 0..8 asc).
__global__ void k_select(const double* __restrict__ accum,
                         int* __restrict__ sel) {
  __shared__ double sc[1024];
  const int t = threadIdx.x;
  const double* a = accum + 4 * t;
  const double S1x = a[0], S2x = a[1], S1y = a[2], S2y = a[3];
  const double N = 47616.0;  // 16*3*32*31
  double mx = S1x / N, my = S1y / N;
  double vx = (S2x - S1x * S1x / N) / (N - 1.0);
  double vy = (S2y - S1y * S1y / N) / (N - 1.0);
  sc[t] = 0.25 * (mx + my) * (vx + vy);
  __syncthreads();
  const double mine = sc[t];
  int rank = 0;
  for (int j = 0; j < 1024; ++j) {
    double vj = sc[j];
    rank += (vj < mine) || (vj == mine && j < t);
  }
  if (rank < 9)          sel[9 + rank]    = t;
  else if (rank >= 1015) sel[rank - 1015] = t;
}

// K3: one block per (image, 8-row output strip). Gather the <=8 needed recon
// rows into LDS, then fused {bilinear 96->224 half-pixel clamp + 3x3 SRM}.
__global__ __launch_bounds__(256) void k_output(const float* __restrict__ x,
                                                const int* __restrict__ sel,
                                                float* __restrict__ out) {
  const int ty  = blockIdx.x;              // 0..27 strip
  const int blk = blockIdx.y;              // 0..95 = set*48 + (b*3+c)
  const int set = blk / 48;
  const int bc  = blk % 48;
  const int y0  = ty * TILE;

  __shared__ float R[8][97];
  __shared__ int   i0t[224];
  __shared__ float frt[224];
  __shared__ int   selm[9];
  const int t = threadIdx.x;

  if (t < 9) selm[t] = sel[set * 9 + t];
  if (t < 224) {
    // src coord = (t+0.5)*96/224 - 0.5 = (3t-2)/7 exactly; edge-renorm == clamp
    int num = 3 * t - 2;
    int i0, fr7;
    if (num < 0) { i0 = 0; fr7 = 0; }
    else {
      i0 = num / 7; fr7 = num - i0 * 7;
      if (i0 >= 95) { i0 = 95; fr7 = 0; }
    }
    i0t[t] = i0;
    frt[t] = (float)fr7 * (1.0f / 7.0f);
  }
  __syncthreads();

  const int Ylo   = max(y0 - 1, 0);
  const int Yhi   = min(y0 + TILE, 223);
  const int sy_lo = i0t[Ylo];
  const int sy_hi = min(i0t[Yhi] + 1, 95);
  const int nrows = sy_hi - sy_lo + 1;     // <= 6

  const float* src = x + (size_t)bc * IMG;
  for (int idx = t; idx < nrows * 96; idx += 256) {
    int ry = idx / 96, xx = idx - ry * 96;
    int sy = sy_lo + ry;
    int gr = sy >> 5, i = sy & 31;
    int gc = xx >> 5, j = xx & 31;
    int pidx = selm[gr * 3 + gc];
    R[ry][xx] = src[(size_t)((pidx >> 5) * 32 + i) * 1024 + (pidx & 31) * 32 + j];
  }
  __syncthreads();

  const float F[3][3] = {{-1.f, 3.f, -1.f}, {3.f, -8.f, 3.f}, {-1.f, 3.f, -1.f}};
  float* o = out + (size_t)blk * (224 * 224);

  for (int idx = t; idx < TILE * 224; idx += 256) {
    int yy = idx / 224;
    int xx = idx - yy * 224;
    int y  = y0 + yy;
    float acc = 0.f;
#pragma unroll
    for (int dy = 0; dy < 3; ++dy) {
      int Y = y + dy - 1;
      if ((unsigned)Y >= 224u) continue;     // zero padding
      int   iy0 = i0t[Y] - sy_lo;
      int   iy1 = min(i0t[Y] + 1, 95) - sy_lo;
      float fy  = frt[Y];
#pragma unroll
      for (int dx = 0; dx < 3; ++dx) {
        int X = xx + dx - 1;
        if ((unsigned)X >= 224u) continue;   // zero padding
        int   ix0 = i0t[X];
        int   ix1 = min(ix0 + 1, 95);
        float fx  = frt[X];
        float v00 = R[iy0][ix0], v01 = R[iy0][ix1];
        float v10 = R[iy1][ix0], v11 = R[iy1][ix1];
        float top = v00 + fx * (v01 - v00);
        float bot = v10 + fx * (v11 - v10);
        float val = top + fy * (bot - top);
        acc += F[dy][dx] * val;
      }
    }
    o[(size_t)y * 224 + xx] = acc;
  }
}

extern "C" void kernel_launch(void* const* d_in, const int* in_sizes, int n_in,
                              void* d_out, int out_size, void* d_ws, size_t ws_size,
                              hipStream_t stream) {
  const float* x = (const float*)d_in[0];
  float* out = (float*)d_out;

  double* accum = (double*)d_ws;                     // 1024*4*8 = 32 KB
  int*    sel   = (int*)((char*)d_ws + 32768);       // 18 * 4 B

  hipMemsetAsync(d_ws, 0, 32768, stream);
  k_score <<<dim3(32, 48), 256, 0, stream>>>(x, accum);
  k_select<<<1, 1024, 0, stream>>>(accum, sel);
  k_output<<<dim3(28, 96), 256, 0, stream>>>(x, sel, out);
}

// Round 3
// 76.611 us; speedup vs baseline: 4.0282x; 1.4702x over previous
//
#include <hip/hip_runtime.h>

// ---------------------------------------------------------------------------
// TextureAnalysisModule: x (16,3,1024,1024) f32
//  k_score    : per-(patch,slice) |dx|,|dy| partial sums (f64, no atomics)
//  k_finalize : reduce 48 slices -> 1024 scores
//  k_rank     : stable rank-by-counting, scatter top9/bot9 indices
//  k_output   : gather patches -> R -> H (x-bilinear) -> U (y-bilinear) -> SRM
//  out: (2,16,3,224,224) f32
// ---------------------------------------------------------------------------

#define NSLICE 48
#define IMG    1048576
#define TILE   8

// --- K1: one block per (patch-row, slice); contiguous 32x1024 strip. -------
__global__ __launch_bounds__(256) void k_score(const float* __restrict__ x,
                                               double* __restrict__ part) {
  const int ph = blockIdx.x;   // patch row 0..31
  const int s  = blockIdx.y;   // slice 0..47
  const int t  = threadIdx.x;
  const float* base = x + (size_t)s * IMG + (size_t)ph * 32768 + 4 * t;

  double s1x = 0.0, s2x = 0.0, s1y = 0.0, s2y = 0.0;
  const bool has_d3 = (t & 7) != 7;   // col 4t+3 is not a patch boundary

#define LD(r) (*(const float4*)(base + (size_t)(r) * 1024))
#define DX(v) { float nx = __shfl_down((v).x, 1);                              \
    float d0 = fabsf((v).y-(v).x), d1 = fabsf((v).z-(v).y), d2 = fabsf((v).w-(v).z); \
    s1x += d0; s2x += (double)d0*d0;                                           \
    s1x += d1; s2x += (double)d1*d1;                                           \
    s1x += d2; s2x += (double)d2*d2;                                           \
    if (has_d3) { float d3 = fabsf(nx-(v).w); s1x += d3; s2x += (double)d3*d3; } }
#define DY(a,b) { float e0 = fabsf((b).x-(a).x), e1 = fabsf((b).y-(a).y),      \
                        e2 = fabsf((b).z-(a).z), e3 = fabsf((b).w-(a).w);      \
    s1y += e0; s2y += (double)e0*e0;                                           \
    s1y += e1; s2y += (double)e1*e1;                                           \
    s1y += e2; s2y += (double)e2*e2;                                           \
    s1y += e3; s2y += (double)e3*e3; }

  float4 v0 = LD(0);
  for (int r = 0; r < 32; r += 4) {
    float4 v1 = LD(r + 1);
    float4 v2 = LD(r + 2);
    float4 v3 = LD(r + 3);
    float4 v4;
    const bool more = (r + 4 < 32);
    if (more) v4 = LD(r + 4);
    DX(v0); DX(v1); DX(v2); DX(v3);
    DY(v0, v1); DY(v1, v2); DY(v2, v3);
    if (more) { DY(v3, v4); v0 = v4; }
  }
#undef LD
#undef DX
#undef DY

  // reduce within each 8-lane group (one patch per group)
#pragma unroll
  for (int off = 4; off > 0; off >>= 1) {
    s1x += __shfl_down(s1x, off, 8);
    s2x += __shfl_down(s2x, off, 8);
    s1y += __shfl_down(s1y, off, 8);
    s2y += __shfl_down(s2y, off, 8);
  }
  if ((t & 7) == 0) {
    const int p = ph * 32 + (t >> 3);
    part[(size_t)(0 * NSLICE + s) * 1024 + p] = s1x;
    part[(size_t)(1 * NSLICE + s) * 1024 + p] = s2x;
    part[(size_t)(2 * NSLICE + s) * 1024 + p] = s1y;
    part[(size_t)(3 * NSLICE + s) * 1024 + p] = s2y;
  }
}

// --- K2: reduce slices -> scores (coalesced stride-1024 loads). ------------
__global__ __launch_bounds__(256) void k_finalize(const double* __restrict__ part,
                                                  double* __restrict__ scores) {
  const int p = blockIdx.x * 256 + threadIdx.x;
  double S[4];
#pragma unroll
  for (int q = 0; q < 4; ++q) {
    const double* b = part + (size_t)q * NSLICE * 1024 + p;
    double a = 0.0;
    for (int s = 0; s < NSLICE; ++s) a += b[(size_t)s * 1024];
    S[q] = a;
  }
  const double N = 47616.0;  // 16*3*32*31
  double mx = S[0] / N, my = S[2] / N;
  double vx = (S[1] - S[0] * S[0] / N) / (N - 1.0);
  double vy = (S[3] - S[2] * S[2] / N) / (N - 1.0);
  scores[p] = 0.25 * (mx + my) * (vx + vy);
}

// --- K3: stable rank; 8 lanes per candidate, 32 candidates per block. ------
// sel[0..8] = rich (ranks 1015..1023 asc), sel[9..17] = poor (ranks 0..8 asc).
__global__ __launch_bounds__(256) void k_rank(const double* __restrict__ scores,
                                              int* __restrict__ sel) {
  __shared__ double sc[1024];
  const int t = threadIdx.x;
  for (int i = t; i < 1024; i += 256) sc[i] = scores[i];
  __syncthreads();

  const int c = blockIdx.x * 32 + (t >> 3);
  const double mine = sc[c];
  int rank = 0;
  for (int j = (t & 7); j < 1024; j += 8) {
    double vj = sc[j];
    rank += (vj < mine) || (vj == mine && j < c);
  }
#pragma unroll
  for (int off = 4; off > 0; off >>= 1) rank += __shfl_down(rank, off, 8);
  if ((t & 7) == 0) {
    if (rank < 9)          sel[9 + rank]    = c;
    else if (rank >= 1015) sel[rank - 1015] = c;
  }
}

// --- K4: one block per (image, 8-row output strip). ------------------------
// R (<=6x96 src rows) -> H (x-bilinear, <=6x224) -> U (y-bilinear, 10x224)
// -> 3x3 SRM conv with zero padding.
__global__ __launch_bounds__(256) void k_output(const float* __restrict__ x,
                                                const int* __restrict__ sel,
                                                float* __restrict__ out) {
  const int ty  = blockIdx.x;              // 0..27
  const int blk = blockIdx.y;              // 0..95 = set*48 + (b*3+c)
  const int set = blk / 48;
  const int bc  = blk % 48;
  const int y0  = ty * TILE;

  __shared__ int   i0t[224];
  __shared__ float frt[224];
  __shared__ float R[6][97];
  __shared__ float H[6][224];
  __shared__ float U[10][224];
  __shared__ int   selm[9];
  const int t = threadIdx.x;

  if (t < 9) selm[t] = sel[set * 9 + t];
  if (t < 224) {
    // src coord = (t+0.5)*96/224 - 0.5 = (3t-2)/7 ; edge renorm == clamp
    int num = 3 * t - 2;
    int i0, fr7;
    if (num < 0) { i0 = 0; fr7 = 0; }
    else {
      i0 = num / 7; fr7 = num - i0 * 7;
      if (i0 >= 95) { i0 = 95; fr7 = 0; }
    }
    i0t[t] = i0;
    frt[t] = (float)fr7 * (1.0f / 7.0f);
  }
  __syncthreads();

  const int Ylo   = max(y0 - 1, 0);
  const int Yhi   = min(y0 + TILE, 223);
  const int sy_lo = i0t[Ylo];
  const int sy_hi = min(i0t[Yhi] + 1, 95);
  const int nrows = sy_hi - sy_lo + 1;     // <= 6

  // gather source rows
  const float* src = x + (size_t)bc * IMG;
  for (int idx = t; idx < nrows * 96; idx += 256) {
    int ry = idx / 96, xx = idx - ry * 96;
    int sy = sy_lo + ry;
    int gr = sy >> 5, i = sy & 31;
    int gc = xx >> 5, j = xx & 31;
    int pidx = selm[gr * 3 + gc];
    R[ry][xx] = src[(size_t)((pidx >> 5) * 32 + i) * 1024 + (pidx & 31) * 32 + j];
  }
  __syncthreads();

  // horizontal bilinear: H[r][X]
  for (int idx = t; idx < nrows * 224; idx += 256) {
    int r = idx / 224, X = idx - r * 224;
    int ix0 = i0t[X], ix1 = min(ix0 + 1, 95);
    float fx = frt[X];
    float a = R[r][ix0], b = R[r][ix1];
    H[r][X] = a + fx * (b - a);
  }
  __syncthreads();

  // vertical bilinear: U[yy][X], Y = y0-1+yy for yy in [0,10)
  for (int idx = t; idx < 10 * 224; idx += 256) {
    int yy = idx / 224, X = idx - yy * 224;
    int Y = y0 - 1 + yy;
    if ((unsigned)Y < 224u) {
      int a = i0t[Y] - sy_lo;
      int b = min(i0t[Y] + 1, 95) - sy_lo;
      float fy = frt[Y];
      float h0 = H[a][X], h1 = H[b][X];
      U[yy][X] = h0 + fy * (h1 - h0);
    }
  }
  __syncthreads();

  // 3x3 SRM conv (zero padding)
  const float F[3][3] = {{-1.f, 3.f, -1.f}, {3.f, -8.f, 3.f}, {-1.f, 3.f, -1.f}};
  float* o = out + (size_t)blk * (224 * 224);
  for (int idx = t; idx < TILE * 224; idx += 256) {
    int yy = idx / 224;
    int xx = idx - yy * 224;
    int y  = y0 + yy;
    float acc = 0.f;
#pragma unroll
    for (int dy = 0; dy < 3; ++dy) {
      int Y = y + dy - 1;
      if ((unsigned)Y >= 224u) continue;
      const float* Ur = U[yy + dy];        // row Y = y0-1+(yy+dy)
#pragma unroll
      for (int dx = 0; dx < 3; ++dx) {
        int X = xx + dx - 1;
        if ((unsigned)X >= 224u) continue;
        acc += F[dy][dx] * Ur[X];
      }
    }
    o[(size_t)y * 224 + xx] = acc;
  }
}

extern "C" void kernel_launch(void* const* d_in, const int* in_sizes, int n_in,
                              void* d_out, int out_size, void* d_ws, size_t ws_size,
                              hipStream_t stream) {
  const float* x = (const float*)d_in[0];
  float* out = (float*)d_out;

  double* part   = (double*)d_ws;                          // 4*48*1024*8 = 1.5 MB
  double* scores = (double*)((char*)d_ws + 1572864);       // 8 KB
  int*    sel    = (int*)((char*)d_ws + 1581056);          // 72 B

  k_score   <<<dim3(32, 48), 256, 0, stream>>>(x, part);
  k_finalize<<<4, 256, 0, stream>>>(part, scores);
  k_rank    <<<32, 256, 0, stream>>>(scores, sel);
  k_output  <<<dim3(28, 96), 256, 0, stream>>>(x, sel, out);
}